// Round 3
// baseline (208.643 us; speedup 1.0000x reference)
//
#include <hip/hip_runtime.h>
#include <hip/hip_bf16.h>

typedef __bf16 bf16;
typedef __bf16 bf16x4 __attribute__((ext_vector_type(4)));
typedef __bf16 bf16x8 __attribute__((ext_vector_type(8)));
typedef float f32x4 __attribute__((ext_vector_type(4)));

typedef __attribute__((address_space(3))) void lds_void;
typedef const __attribute__((address_space(1))) void gbl_void;

#define D_MODEL 1024
#define NHEAD 16
#define DEPTH 64
#define SEQ 2048
#define BATCH 2
#define NTOK (BATCH * SEQ)   // 4096

// 1/sqrt(64) * log2(e): folded into q so attention exp is a bare exp2.
#define Q_SCALE 0.18033688f

// ---------------------------------------------------------------------------
// Kernel 1: prep = weight transpose+convert (z=0..3) + x convert (z=4..7).
// ---------------------------------------------------------------------------
__global__ __launch_bounds__(256) void prep(const float* __restrict__ w0,
                                            const float* __restrict__ w1,
                                            const float* __restrict__ w2,
                                            const float* __restrict__ w3,
                                            const float* __restrict__ x,
                                            bf16* __restrict__ wtb,
                                            bf16* __restrict__ xb) {
    int z = blockIdx.z;
    int tx = threadIdx.x, ty = threadIdx.y;   // (32, 8)
    if (z < 4) {
        const float* w = (z == 0) ? w0 : (z == 1) ? w1 : (z == 2) ? w2 : w3;
        bf16* d = wtb + (size_t)z * D_MODEL * D_MODEL;
        __shared__ float tile[32][33];
        int c0 = blockIdx.x * 32;   // source col block (n)
        int r0 = blockIdx.y * 32;   // source row block (k)
#pragma unroll
        for (int i = 0; i < 4; i++)
            tile[ty + i * 8][tx] = w[(size_t)(r0 + ty + i * 8) * D_MODEL + c0 + tx];
        __syncthreads();
#pragma unroll
        for (int i = 0; i < 4; i++)
            d[(size_t)(c0 + ty + i * 8) * D_MODEL + r0 + tx] = (bf16)tile[tx][ty + i * 8];
    } else {
        int t = ty * 32 + tx;
        size_t i = ((size_t)(z - 4) * 1024 + blockIdx.y * 32 + blockIdx.x) * 256 + t;
        float4 v = ((const float4*)x)[i];
        bf16x4 o = {(bf16)v.x, (bf16)v.y, (bf16)v.z, (bf16)v.w};
        *(bf16x4*)&xb[i * 4] = o;
    }
}

// ---------------------------------------------------------------------------
// Kernel 2: QKV projection, 256x256 tile, BK=64, 8 waves, 8-phase counted
// vmcnt schedule (unchanged this round).
// ---------------------------------------------------------------------------
__global__ __launch_bounds__(512, 2) void qkv_gemm(const bf16* __restrict__ xb,
                                                   const bf16* __restrict__ wtb,
                                                   const float* __restrict__ bq,
                                                   const float* __restrict__ bk,
                                                   const float* __restrict__ bv,
                                                   bf16* __restrict__ q,
                                                   bf16* __restrict__ k,
                                                   bf16* __restrict__ v) {
    __shared__ bf16 sm[65536];   // 128 KiB

    const int flat = blockIdx.x;
    const int wg = (flat & 7) * 24 + (flat >> 3);
    const int mt = wg & 15, nt = wg >> 4;     // wg = nt*16 + mt
    const int row0 = mt << 8;                 // token base
    const int z = nt >> 2;                    // 0=q 1=k 2=v
    const int nb = (nt & 3) << 8;             // feature base within z

    const int tid = threadIdx.x;
    const int lane = tid & 63, wave = tid >> 6;
    const int wm = wave >> 2, wn = wave & 3;  // 2 x 4 wave grid
    const int quad = lane >> 4, l16 = lane & 15;
    const int kch = ((quad ^ ((l16 >> 1) & 3)) << 3);   // swizzled 16B chunk (elems)

    const int srow = lane >> 2;
    const int scg = (lane & 3) ^ ((lane >> 3) & 3);     // pre-swizzled src chunk
    const int stDst = wave * 1024 + lane * 8;           // elems within half

    const bf16* Ag = xb + (size_t)(row0 + wave * 32 + srow) * D_MODEL + scg * 8;
    const bf16* Bg = wtb + (size_t)z * D_MODEL * D_MODEL
                   + (size_t)(nb + wave * 32 + srow) * D_MODEL + scg * 8;

    f32x4 acc[8][4] = {};
    bf16x8 bfr[4];

#define GLL(SRC, DST) __builtin_amdgcn_global_load_lds((gbl_void*)(SRC), (lds_void*)(DST), 16, 0, 0)
#define STG_A(T_, KQ_, BUF_) { \
    const bf16* s_ = Ag + (T_) * 64 + (KQ_) * 32; \
    bf16* d_ = sm + (BUF_) * 16384 + (KQ_) * 8192 + stDst; \
    GLL(s_, d_); GLL(s_ + 16 * D_MODEL, d_ + 512); }
#define STG_B(T_, KQ_, BUF_) { \
    const bf16* s_ = Bg + (T_) * 64 + (KQ_) * 32; \
    bf16* d_ = sm + 32768 + (BUF_) * 16384 + (KQ_) * 8192 + stDst; \
    GLL(s_, d_); GLL(s_ + 16 * D_MODEL, d_ + 512); }
#define WAIT6 { asm volatile("s_waitcnt vmcnt(6)" ::: "memory"); }
#define NOW

#define PHASE(BUF_, KQ_, MQ_, STG_STMT, WAIT_STMT) { \
    bf16x8 af[4]; \
    const int ab_ = (BUF_) * 16384 + (KQ_) * 8192 + (wm * 128 + (MQ_) * 64 + l16) * 32 + kch; \
    _Pragma("unroll") \
    for (int i_ = 0; i_ < 4; i_++) af[i_] = *(const bf16x8*)&sm[ab_ + i_ * 512]; \
    if ((MQ_) == 0) { \
        const int bb_ = 32768 + (BUF_) * 16384 + (KQ_) * 8192 + (wn * 64 + l16) * 32 + kch; \
        _Pragma("unroll") \
        for (int j_ = 0; j_ < 4; j_++) bfr[j_] = *(const bf16x8*)&sm[bb_ + j_ * 512]; \
    } \
    STG_STMT; \
    WAIT_STMT; \
    __builtin_amdgcn_sched_barrier(0); \
    __builtin_amdgcn_s_barrier(); \
    __builtin_amdgcn_s_setprio(1); \
    _Pragma("unroll") \
    for (int i_ = 0; i_ < 4; i_++) \
        _Pragma("unroll") \
        for (int j_ = 0; j_ < 4; j_++) \
            acc[(MQ_) * 4 + i_][j_] = __builtin_amdgcn_mfma_f32_16x16x32_bf16( \
                af[i_], bfr[j_], acc[(MQ_) * 4 + i_][j_], 0, 0, 0); \
    __builtin_amdgcn_s_setprio(0); \
    __builtin_amdgcn_sched_barrier(0); \
    __builtin_amdgcn_s_barrier(); }

    STG_B(0, 0, 0);
    STG_A(0, 0, 0);
    STG_B(0, 1, 0);
    STG_A(0, 1, 0);
    asm volatile("s_waitcnt vmcnt(4)" ::: "memory");
    STG_B(1, 0, 1);
    STG_A(1, 0, 1);
    STG_B(1, 1, 1);
    asm volatile("s_waitcnt vmcnt(6)" ::: "memory");
    __builtin_amdgcn_sched_barrier(0);
    __builtin_amdgcn_s_barrier();

#pragma unroll 1
    for (int it = 0; it < 8; ++it) {
        const int t1 = 2 * it + 1;
        const int t2 = (2 * it + 2) & 15;   // wrap keeps vmcnt counts exact at tail
        const int t3 = (2 * it + 3) & 15;
        PHASE(0, 0, 0, STG_A(t1, 1, 1), NOW)      // ph1
        PHASE(0, 0, 1, STG_B(t2, 0, 0), NOW)      // ph2
        PHASE(0, 1, 0, STG_A(t2, 0, 0), NOW)      // ph3
        PHASE(0, 1, 1, STG_B(t2, 1, 0), WAIT6)    // ph4
        PHASE(1, 0, 0, STG_A(t2, 1, 0), NOW)      // ph5
        PHASE(1, 0, 1, STG_B(t3, 0, 1), NOW)      // ph6
        PHASE(1, 1, 0, STG_A(t3, 0, 1), NOW)      // ph7
        PHASE(1, 1, 1, STG_B(t3, 1, 1), WAIT6)    // ph8
    }

#undef PHASE
#undef WAIT6
#undef NOW
#undef STG_A
#undef STG_B
#undef GLL

    const float* bias = (z == 0) ? bq : (z == 1) ? bk : bv;
    const int bI = row0 >> 11;
    const int sBase = row0 & 2047;
    if (z < 2) {
        bf16* dst = (z == 0) ? q : k;   // [B,H,S,64]
        const float scl = (z == 0) ? Q_SCALE : 1.0f;
#pragma unroll
        for (int j = 0; j < 4; j++) {
            const int f = nb + wn * 64 + j * 16 + l16;
            const float bi = bias[f];
            const int hh = f >> 6, d = f & 63;
            bf16* dcol = dst + ((size_t)(bI * NHEAD + hh) * SEQ) * DEPTH + d;
#pragma unroll
            for (int mi = 0; mi < 8; mi++) {
                const int s0 = sBase + wm * 128 + (mi >> 2) * 64 + (mi & 3) * 16 + quad * 4;
#pragma unroll
                for (int r = 0; r < 4; r++)
                    dcol[(size_t)(s0 + r) * DEPTH] = (bf16)((acc[mi][j][r] + bi) * scl);
            }
        }
    } else {
#pragma unroll
        for (int j = 0; j < 4; j++) {
            const int f = nb + wn * 64 + j * 16 + l16;
            const float bi = bias[f];
            const int hh = f >> 6, d = f & 63;
            bf16* vrow = v + ((size_t)(bI * NHEAD + hh) * DEPTH + d) * SEQ;
#pragma unroll
            for (int mi = 0; mi < 8; mi++) {
                const int s0 = sBase + wm * 128 + (mi >> 2) * 64 + (mi & 3) * 16 + quad * 4;
                f32x4 a = acc[mi][j];
                bf16x4 ob = {(bf16)(a[0] + bi), (bf16)(a[1] + bi),
                             (bf16)(a[2] + bi), (bf16)(a[3] + bi)};
                *(bf16x4*)&vrow[s0] = ob;
            }
        }
    }
}

// ---------------------------------------------------------------------------
// Kernel 3: flash attention, R6: kv-split waves, ZERO LDS in main loop.
// Block = 64 q rows x head; 4 waves; outer tile = 128 kv tokens; wave w owns
// tokens [w*32, w*32+32) of each tile.  Per wave-lane token map (chosen so
// PV fragments are contiguous): QK^T M-row m=l16 of half h -> token
// t0 + w*32 + (l16>>2)*8 + h*4 + (l16&3); then S-acc (row=kv=quad*4+r,
// col=q=l16) IS the PV B-fragment (k=quad*8+(h*4+r) <-> token
// t0+w*32+quad*8+e, consecutive) after exp2+bf16-cvt -- P stays in regs.
// K loaded global->reg per-lane (b128 x4/iter), V^T global->reg (b128 x4,
// 8 consecutive tokens per lane).  All data L2-resident (XCD-pinned: block
// id = bh + 32*qb -> XCD bh%8, 4 heads = 2MB KV per XCD L2).  No barriers
// in loop; one LDS f32 reduction over the 4 kv-partial waves at the end.
// Row-sums accumulated in VALU (quad-partial), reduced with ctx.
// ---------------------------------------------------------------------------
__global__ __launch_bounds__(256, 2) void attn(const bf16* __restrict__ q,
                                               const bf16* __restrict__ k,
                                               const bf16* __restrict__ v,
                                               bf16* __restrict__ ctx) {
    __shared__ f32x4 red[4][17][64];    // [wave][16 ov tiles + lsum][lane]
    const int tid = threadIdx.x;
    const int lane = tid & 63, wave = tid >> 6;
    const int quad = lane >> 4, l16 = lane & 15;
    const int bh = blockIdx.x;
    const int q0 = blockIdx.y * 64;
    const size_t hb = (size_t)bh * SEQ * DEPTH;
    const bf16* qh = q + hb;
    const bf16* kh = k + hb;            // [S][64]
    const bf16* vh = v + hb;            // [64][S]

    // Q as B-fragments: block's 64 q rows, shared by all waves
    bf16x8 bq_[4][2];
#pragma unroll
    for (int n = 0; n < 4; n++) {
        int qrow = q0 + n * 16 + l16;
#pragma unroll
        for (int c = 0; c < 2; c++)
            bq_[n][c] = *(const bf16x8*)&qh[(size_t)qrow * DEPTH + c * 32 + quad * 8];
    }

    // per-lane fixed offsets
    const int klane = (wave * 32 + (l16 >> 2) * 8 + (l16 & 3)) * DEPTH + quad * 8;
    const int vlane = l16 * SEQ + wave * 32 + quad * 8;

    f32x4 ov[4][4] = {};                  // [d-tile][q-tile] kv-partial ctx^T
    float lsum[4] = {0.f, 0.f, 0.f, 0.f}; // [q-tile] quad-partial row sums

    bf16x8 ka[2][2], kb2[2][2];           // K frags [h][c], double-buffered

#define LOADK(KF, T_) { \
    const bf16* kp_ = kh + (size_t)(T_) * DEPTH + klane; \
    KF[0][0] = *(const bf16x8*)(kp_); \
    KF[0][1] = *(const bf16x8*)(kp_ + 32); \
    KF[1][0] = *(const bf16x8*)(kp_ + 256); \
    KF[1][1] = *(const bf16x8*)(kp_ + 288); }

#define COMPUTE(KF, T_) { \
    bf16x8 vf[4]; \
    _Pragma("unroll") \
    for (int t_ = 0; t_ < 4; t_++) \
        vf[t_] = *(const bf16x8*)(vh + (size_t)t_ * 16 * SEQ + vlane + (T_)); \
    f32x4 s0[4] = {}, s1[4] = {}; \
    _Pragma("unroll") \
    for (int n_ = 0; n_ < 4; n_++) { \
        s0[n_] = __builtin_amdgcn_mfma_f32_16x16x32_bf16(KF[0][0], bq_[n_][0], s0[n_], 0, 0, 0); \
        s0[n_] = __builtin_amdgcn_mfma_f32_16x16x32_bf16(KF[0][1], bq_[n_][1], s0[n_], 0, 0, 0); \
        s1[n_] = __builtin_amdgcn_mfma_f32_16x16x32_bf16(KF[1][0], bq_[n_][0], s1[n_], 0, 0, 0); \
        s1[n_] = __builtin_amdgcn_mfma_f32_16x16x32_bf16(KF[1][1], bq_[n_][1], s1[n_], 0, 0, 0); \
    } \
    bf16x8 pb[4]; \
    _Pragma("unroll") \
    for (int n_ = 0; n_ < 4; n_++) { \
        float e0a = __builtin_amdgcn_exp2f(s0[n_][0]); \
        float e0b = __builtin_amdgcn_exp2f(s0[n_][1]); \
        float e0c = __builtin_amdgcn_exp2f(s0[n_][2]); \
        float e0d = __builtin_amdgcn_exp2f(s0[n_][3]); \
        float e1a = __builtin_amdgcn_exp2f(s1[n_][0]); \
        float e1b = __builtin_amdgcn_exp2f(s1[n_][1]); \
        float e1c = __builtin_amdgcn_exp2f(s1[n_][2]); \
        float e1d = __builtin_amdgcn_exp2f(s1[n_][3]); \
        pb[n_][0] = (bf16)e0a; pb[n_][1] = (bf16)e0b; \
        pb[n_][2] = (bf16)e0c; pb[n_][3] = (bf16)e0d; \
        pb[n_][4] = (bf16)e1a; pb[n_][5] = (bf16)e1b; \
        pb[n_][6] = (bf16)e1c; pb[n_][7] = (bf16)e1d; \
        lsum[n_] += ((e0a + e0b) + (e0c + e0d)) + ((e1a + e1b) + (e1c + e1d)); \
    } \
    _Pragma("unroll") \
    for (int t_ = 0; t_ < 4; t_++) \
        _Pragma("unroll") \
        for (int n_ = 0; n_ < 4; n_++) \
            ov[t_][n_] = __builtin_amdgcn_mfma_f32_16x16x32_bf16(vf[t_], pb[n_], ov[t_][n_], 0, 0, 0); }

    LOADK(ka, 0);
#pragma unroll 1
    for (int t0 = 0; t0 < SEQ; t0 += 256) {
        LOADK(kb2, t0 + 128);
        COMPUTE(ka, t0);
        LOADK(ka, (t0 + 256) & (SEQ - 1));   // wrap: valid mem, data unused
        COMPUTE(kb2, t0 + 128);
    }
#undef COMPUTE
#undef LOADK

    // cross-wave reduction of kv-partials (once per block)
#pragma unroll
    for (int t = 0; t < 4; t++)
#pragma unroll
        for (int n = 0; n < 4; n++)
            red[wave][t * 4 + n][lane] = ov[t][n];
    f32x4 lv = {lsum[0], lsum[1], lsum[2], lsum[3]};
    red[wave][16][lane] = lv;
    __syncthreads();

    // lsum total: sum over 4 waves x 4 quad-partials (broadcast reads)
    f32x4 ls = {};
#pragma unroll
    for (int w_ = 0; w_ < 4; w_++)
#pragma unroll
        for (int q_ = 0; q_ < 4; q_++)
            ls += red[w_][16][l16 + q_ * 16];
    f32x4 inv4 = {1.0f / ls[0], 1.0f / ls[1], 1.0f / ls[2], 1.0f / ls[3]};

    // this wave reduces & stores d-tile t = wave
    const int b = bh >> 4, hh = bh & 15;
#pragma unroll
    for (int n = 0; n < 4; n++) {
        f32x4 s = red[0][wave * 4 + n][lane] + red[1][wave * 4 + n][lane]
                + red[2][wave * 4 + n][lane] + red[3][wave * 4 + n][lane];
        float iv = inv4[n];
        bf16x4 ob = {(bf16)(s[0] * iv), (bf16)(s[1] * iv),
                     (bf16)(s[2] * iv), (bf16)(s[3] * iv)};
        size_t off = ((size_t)(b * SEQ + q0 + n * 16 + l16)) * D_MODEL
                   + hh * 64 + wave * 16 + quad * 4;
        *(bf16x4*)&ctx[off] = ob;
    }
}

// ---------------------------------------------------------------------------
// Kernel 4: output projection (unchanged this round).
// ---------------------------------------------------------------------------
__global__ __launch_bounds__(256) void out_gemm(const bf16* __restrict__ ctx,
                                                const bf16* __restrict__ wot,
                                                const float* __restrict__ bo,
                                                float* __restrict__ out) {
    __shared__ bf16 As[64 * 32];
    __shared__ bf16 Bs[128 * 32];
    const int tid = threadIdx.x;
    const int lane = tid & 63, wave = tid >> 6;
    const int quad = lane >> 4, l16 = lane & 15;
    const int srow = lane >> 2, selem = (lane & 3) * 8;
    int row0 = blockIdx.y * 64, col0 = blockIdx.x * 128;
    f32x4 acc[4][2] = {};

    for (int k0 = 0; k0 < D_MODEL; k0 += 32) {
        __syncthreads();
        {
            const bf16* ga = ctx + (size_t)(row0 + wave * 16 + srow) * D_MODEL + k0 + selem;
            __builtin_amdgcn_global_load_lds((gbl_void*)ga, (lds_void*)(As + wave * 512 + lane * 8), 16, 0, 0);
        }
#pragma unroll
        for (int t = 0; t < 2; t++) {
            int m = wave * 2 + t;
            const bf16* gb = wot + (size_t)(col0 + m * 16 + srow) * D_MODEL + k0 + selem;
            __builtin_amdgcn_global_load_lds((gbl_void*)gb, (lds_void*)(Bs + m * 512 + lane * 8), 16, 0, 0);
        }
        __syncthreads();
        bf16x8 af[4], bfr[2];
#pragma unroll
        for (int i = 0; i < 4; i++)
            af[i] = *(const bf16x8*)&As[(i * 16 + l16) * 32 + quad * 8];
#pragma unroll
        for (int j = 0; j < 2; j++)
            bfr[j] = *(const bf16x8*)&Bs[(wave * 32 + j * 16 + l16) * 32 + quad * 8];
#pragma unroll
        for (int i = 0; i < 4; i++)
#pragma unroll
            for (int j = 0; j < 2; j++)
                acc[i][j] = __builtin_amdgcn_mfma_f32_16x16x32_bf16(af[i], bfr[j], acc[i][j], 0, 0, 0);
    }
#pragma unroll
    for (int i = 0; i < 4; i++)
#pragma unroll
        for (int j = 0; j < 2; j++) {
            int colg = col0 + wave * 32 + j * 16 + l16;
            float bi = bo[colg];
            int rbase = row0 + i * 16 + quad * 4;
#pragma unroll
            for (int r = 0; r < 4; r++)
                out[(size_t)(rbase + r) * D_MODEL + colg] = acc[i][j][r] + bi;
        }
}

// ---------------------------------------------------------------------------
extern "C" void kernel_launch(void* const* d_in, const int* in_sizes, int n_in,
                              void* d_out, int out_size, void* d_ws, size_t ws_size,
                              hipStream_t stream) {
    const float* x  = (const float*)d_in[0];
    const float* wq = (const float*)d_in[1];
    const float* bq = (const float*)d_in[2];
    const float* wk = (const float*)d_in[3];
    const float* bk = (const float*)d_in[4];
    const float* wv = (const float*)d_in[5];
    const float* bv = (const float*)d_in[6];
    const float* wo = (const float*)d_in[7];
    const float* bo = (const float*)d_in[8];
    float* out = (float*)d_out;

    const size_t MB = 1024 * 1024;
    char* ws = (char*)d_ws;
    bf16* xb  = (bf16*)(ws);             // [4096][1024]            8 MB
    bf16* wtb = (bf16*)(ws + 8 * MB);    // [4][1024][1024] (N,K)   8 MB
    bf16* qb  = (bf16*)(ws + 16 * MB);   // [B,H,S,64] (scaled)     8 MB
    bf16* kb  = (bf16*)(ws + 24 * MB);   // [B,H,S,64]              8 MB
    bf16* vb  = (bf16*)(ws + 32 * MB);   // [B,H,64,S]              8 MB
    bf16* ctx = (bf16*)(ws + 40 * MB);   // [4096][1024]            8 MB

    prep<<<dim3(32, 32, 8), dim3(32, 8), 0, stream>>>(wq, wk, wv, wo, x, wtb, xb);
    qkv_gemm<<<dim3(192), dim3(512), 0, stream>>>(xb, wtb, bq, bk, bv, qb, kb, vb);
    attn<<<dim3(BATCH * NHEAD, SEQ / 64), 256, 0, stream>>>(qb, kb, vb, ctx);
    out_gemm<<<dim3(8, 64), 256, 0, stream>>>(ctx, wtb + 3 * (size_t)D_MODEL * D_MODEL, bo, out);
}

// Round 4
// 200.881 us; speedup vs baseline: 1.0386x; 1.0386x over previous
//
#include <hip/hip_runtime.h>
#include <hip/hip_bf16.h>

typedef __bf16 bf16;
typedef __bf16 bf16x4 __attribute__((ext_vector_type(4)));
typedef __bf16 bf16x8 __attribute__((ext_vector_type(8)));
typedef float f32x4 __attribute__((ext_vector_type(4)));

typedef __attribute__((address_space(3))) void lds_void;
typedef const __attribute__((address_space(1))) void gbl_void;

#define D_MODEL 1024
#define NHEAD 16
#define DEPTH 64
#define SEQ 2048
#define BATCH 2
#define NTOK (BATCH * SEQ)   // 4096

// 1/sqrt(64) * log2(e): folded into q so attention exp is a bare exp2.
#define Q_SCALE 0.18033688f

// ---------------------------------------------------------------------------
// Kernel 1: prep = weight transpose+convert (z=0..3) + x convert (z=4..7).
// ---------------------------------------------------------------------------
__global__ __launch_bounds__(256) void prep(const float* __restrict__ w0,
                                            const float* __restrict__ w1,
                                            const float* __restrict__ w2,
                                            const float* __restrict__ w3,
                                            const float* __restrict__ x,
                                            bf16* __restrict__ wtb,
                                            bf16* __restrict__ xb) {
    int z = blockIdx.z;
    int tx = threadIdx.x, ty = threadIdx.y;   // (32, 8)
    if (z < 4) {
        const float* w = (z == 0) ? w0 : (z == 1) ? w1 : (z == 2) ? w2 : w3;
        bf16* d = wtb + (size_t)z * D_MODEL * D_MODEL;
        __shared__ float tile[32][33];
        int c0 = blockIdx.x * 32;   // source col block (n)
        int r0 = blockIdx.y * 32;   // source row block (k)
#pragma unroll
        for (int i = 0; i < 4; i++)
            tile[ty + i * 8][tx] = w[(size_t)(r0 + ty + i * 8) * D_MODEL + c0 + tx];
        __syncthreads();
#pragma unroll
        for (int i = 0; i < 4; i++)
            d[(size_t)(c0 + ty + i * 8) * D_MODEL + r0 + tx] = (bf16)tile[tx][ty + i * 8];
    } else {
        int t = ty * 32 + tx;
        size_t i = ((size_t)(z - 4) * 1024 + blockIdx.y * 32 + blockIdx.x) * 256 + t;
        float4 v = ((const float4*)x)[i];
        bf16x4 o = {(bf16)v.x, (bf16)v.y, (bf16)v.z, (bf16)v.w};
        *(bf16x4*)&xb[i * 4] = o;
    }
}

// ---------------------------------------------------------------------------
// Kernel 2: QKV projection, 256x256 tile, BK=64, 8 waves, 8-phase counted
// vmcnt schedule (unchanged this round).
// ---------------------------------------------------------------------------
__global__ __launch_bounds__(512, 2) void qkv_gemm(const bf16* __restrict__ xb,
                                                   const bf16* __restrict__ wtb,
                                                   const float* __restrict__ bq,
                                                   const float* __restrict__ bk,
                                                   const float* __restrict__ bv,
                                                   bf16* __restrict__ q,
                                                   bf16* __restrict__ k,
                                                   bf16* __restrict__ v) {
    __shared__ bf16 sm[65536];   // 128 KiB

    const int flat = blockIdx.x;
    const int wg = (flat & 7) * 24 + (flat >> 3);
    const int mt = wg & 15, nt = wg >> 4;     // wg = nt*16 + mt
    const int row0 = mt << 8;                 // token base
    const int z = nt >> 2;                    // 0=q 1=k 2=v
    const int nb = (nt & 3) << 8;             // feature base within z

    const int tid = threadIdx.x;
    const int lane = tid & 63, wave = tid >> 6;
    const int wm = wave >> 2, wn = wave & 3;  // 2 x 4 wave grid
    const int quad = lane >> 4, l16 = lane & 15;
    const int kch = ((quad ^ ((l16 >> 1) & 3)) << 3);   // swizzled 16B chunk (elems)

    const int srow = lane >> 2;
    const int scg = (lane & 3) ^ ((lane >> 3) & 3);     // pre-swizzled src chunk
    const int stDst = wave * 1024 + lane * 8;           // elems within half

    const bf16* Ag = xb + (size_t)(row0 + wave * 32 + srow) * D_MODEL + scg * 8;
    const bf16* Bg = wtb + (size_t)z * D_MODEL * D_MODEL
                   + (size_t)(nb + wave * 32 + srow) * D_MODEL + scg * 8;

    f32x4 acc[8][4] = {};
    bf16x8 bfr[4];

#define GLL(SRC, DST) __builtin_amdgcn_global_load_lds((gbl_void*)(SRC), (lds_void*)(DST), 16, 0, 0)
#define STG_A(T_, KQ_, BUF_) { \
    const bf16* s_ = Ag + (T_) * 64 + (KQ_) * 32; \
    bf16* d_ = sm + (BUF_) * 16384 + (KQ_) * 8192 + stDst; \
    GLL(s_, d_); GLL(s_ + 16 * D_MODEL, d_ + 512); }
#define STG_B(T_, KQ_, BUF_) { \
    const bf16* s_ = Bg + (T_) * 64 + (KQ_) * 32; \
    bf16* d_ = sm + 32768 + (BUF_) * 16384 + (KQ_) * 8192 + stDst; \
    GLL(s_, d_); GLL(s_ + 16 * D_MODEL, d_ + 512); }
#define WAIT6 { asm volatile("s_waitcnt vmcnt(6)" ::: "memory"); }
#define NOW

#define PHASE(BUF_, KQ_, MQ_, STG_STMT, WAIT_STMT) { \
    bf16x8 af[4]; \
    const int ab_ = (BUF_) * 16384 + (KQ_) * 8192 + (wm * 128 + (MQ_) * 64 + l16) * 32 + kch; \
    _Pragma("unroll") \
    for (int i_ = 0; i_ < 4; i_++) af[i_] = *(const bf16x8*)&sm[ab_ + i_ * 512]; \
    if ((MQ_) == 0) { \
        const int bb_ = 32768 + (BUF_) * 16384 + (KQ_) * 8192 + (wn * 64 + l16) * 32 + kch; \
        _Pragma("unroll") \
        for (int j_ = 0; j_ < 4; j_++) bfr[j_] = *(const bf16x8*)&sm[bb_ + j_ * 512]; \
    } \
    STG_STMT; \
    WAIT_STMT; \
    __builtin_amdgcn_sched_barrier(0); \
    __builtin_amdgcn_s_barrier(); \
    __builtin_amdgcn_s_setprio(1); \
    _Pragma("unroll") \
    for (int i_ = 0; i_ < 4; i_++) \
        _Pragma("unroll") \
        for (int j_ = 0; j_ < 4; j_++) \
            acc[(MQ_) * 4 + i_][j_] = __builtin_amdgcn_mfma_f32_16x16x32_bf16( \
                af[i_], bfr[j_], acc[(MQ_) * 4 + i_][j_], 0, 0, 0); \
    __builtin_amdgcn_s_setprio(0); \
    __builtin_amdgcn_sched_barrier(0); \
    __builtin_amdgcn_s_barrier(); }

    STG_B(0, 0, 0);
    STG_A(0, 0, 0);
    STG_B(0, 1, 0);
    STG_A(0, 1, 0);
    asm volatile("s_waitcnt vmcnt(4)" ::: "memory");
    STG_B(1, 0, 1);
    STG_A(1, 0, 1);
    STG_B(1, 1, 1);
    asm volatile("s_waitcnt vmcnt(6)" ::: "memory");
    __builtin_amdgcn_sched_barrier(0);
    __builtin_amdgcn_s_barrier();

#pragma unroll 1
    for (int it = 0; it < 8; ++it) {
        const int t1 = 2 * it + 1;
        const int t2 = (2 * it + 2) & 15;   // wrap keeps vmcnt counts exact at tail
        const int t3 = (2 * it + 3) & 15;
        PHASE(0, 0, 0, STG_A(t1, 1, 1), NOW)      // ph1
        PHASE(0, 0, 1, STG_B(t2, 0, 0), NOW)      // ph2
        PHASE(0, 1, 0, STG_A(t2, 0, 0), NOW)      // ph3
        PHASE(0, 1, 1, STG_B(t2, 1, 0), WAIT6)    // ph4
        PHASE(1, 0, 0, STG_A(t2, 1, 0), NOW)      // ph5
        PHASE(1, 0, 1, STG_B(t3, 0, 1), NOW)      // ph6
        PHASE(1, 1, 0, STG_A(t3, 0, 1), NOW)      // ph7
        PHASE(1, 1, 1, STG_B(t3, 1, 1), WAIT6)    // ph8
    }

#undef PHASE
#undef WAIT6
#undef NOW
#undef STG_A
#undef STG_B
#undef GLL

    const float* bias = (z == 0) ? bq : (z == 1) ? bk : bv;
    const int bI = row0 >> 11;
    const int sBase = row0 & 2047;
    if (z < 2) {
        bf16* dst = (z == 0) ? q : k;   // [B,H,S,64]
        const float scl = (z == 0) ? Q_SCALE : 1.0f;
#pragma unroll
        for (int j = 0; j < 4; j++) {
            const int f = nb + wn * 64 + j * 16 + l16;
            const float bi = bias[f];
            const int hh = f >> 6, d = f & 63;
            bf16* dcol = dst + ((size_t)(bI * NHEAD + hh) * SEQ) * DEPTH + d;
#pragma unroll
            for (int mi = 0; mi < 8; mi++) {
                const int s0 = sBase + wm * 128 + (mi >> 2) * 64 + (mi & 3) * 16 + quad * 4;
#pragma unroll
                for (int r = 0; r < 4; r++)
                    dcol[(size_t)(s0 + r) * DEPTH] = (bf16)((acc[mi][j][r] + bi) * scl);
            }
        }
    } else {
#pragma unroll
        for (int j = 0; j < 4; j++) {
            const int f = nb + wn * 64 + j * 16 + l16;
            const float bi = bias[f];
            const int hh = f >> 6, d = f & 63;
            bf16* vrow = v + ((size_t)(bI * NHEAD + hh) * DEPTH + d) * SEQ;
#pragma unroll
            for (int mi = 0; mi < 8; mi++) {
                const int s0 = sBase + wm * 128 + (mi >> 2) * 64 + (mi & 3) * 16 + quad * 4;
                f32x4 a = acc[mi][j];
                bf16x4 ob = {(bf16)(a[0] + bi), (bf16)(a[1] + bi),
                             (bf16)(a[2] + bi), (bf16)(a[3] + bi)};
                *(bf16x4*)&vrow[s0] = ob;
            }
        }
    }
}

// ---------------------------------------------------------------------------
// Kernel 3: flash attention, R7 = R3 dataflow + LDS staging.
// Block = 64 q rows x head, 4 waves; kv tile 128, wave owns 32-kv slice
// (tokens wave*32..+31 of each tile).  K [128][64] and V^T [64][128] staged
// single-buffered in LDS via width-16 global_load_lds with pre-swizzled
// SOURCE chunks (LDS dst linear; G21):
//   K: LDS[r][ch] = K[r][ch ^ s(r)], s(r) = ((r&3)<<1)|((r>>3)&1)
//   V: LDS[d][ch] = V^T[d][ch ^ (d&15)]
// Fragment reads apply the same XOR -> uniform bank spread (<=min cycles).
// P stays in registers (R3's verified token map: QK^T A-row l16 of half h
// reads physical kv row wave*32+(l16>>2)*8+h*4+(l16&3); the S-accumulator
// then IS the PV B-fragment after exp2+cvt).  Row-sums in VALU.  Each K/V
// LDS byte is read exactly once (4 MFMA per ds_read_b128).  Cross-wave
// kv-partial reduction reuses the staging LDS in 2 rounds (36 KB total).
// XCD pinning: block id = bh + 32*qb -> XCD bh%8, 4 heads = 2 MB KV / L2.
// ---------------------------------------------------------------------------
__global__ __launch_bounds__(256) void attn(const bf16* __restrict__ q,
                                            const bf16* __restrict__ k,
                                            const bf16* __restrict__ v,
                                            bf16* __restrict__ ctx) {
    __shared__ __align__(16) char smem[36864];
    bf16* Ks = (bf16*)smem;             // [128][64] swizzled, 16 KB
    bf16* Vs = (bf16*)(smem + 16384);   // [64][128] swizzled, 16 KB
    const int tid = threadIdx.x;
    const int lane = tid & 63, wave = tid >> 6;
    const int quad = lane >> 4, l16 = lane & 15;
    const int bh = blockIdx.x;
    const int q0 = blockIdx.y * 64;
    const size_t hb = (size_t)bh * SEQ * DEPTH;
    const bf16* qh = q + hb;
    const bf16* kh = k + hb;            // [S][64]
    const bf16* vh = v + hb;            // [64][S]

    // Q as B-fragments: block's 64 q rows, shared by all waves
    bf16x8 bq_[4][2];
#pragma unroll
    for (int n = 0; n < 4; n++) {
        int qrow = q0 + n * 16 + l16;
#pragma unroll
        for (int c = 0; c < 2; c++)
            bq_[n][c] = *(const bf16x8*)&qh[(size_t)qrow * DEPTH + c * 32 + quad * 8];
    }

    f32x4 ov[4][4] = {};   // [d-tile][q-tile] kv-partial ctx^T
    f32x4 lv = {};         // [q-tile] quad-partial row sums

    // staging geometry (LDS dst linear; source chunk pre-swizzled)
    const int krow = wave * 32 + (lane >> 3);            // + o*8
    const int kchS = (lane & 7) ^ (((lane >> 3) & 3) << 1);  // ^ (o&1)
    const int vrow = wave * 16 + (lane >> 4);            // + o*4
    // fragment-read geometry
    const int krdRow = wave * 32 + ((l16 >> 2) << 3) + (l16 & 3);  // + h*4
    const int ksw = ((l16 & 3) << 1) | ((l16 >> 2) & 1);
    const int vrd = (((wave << 2) | quad) ^ l16) << 3;   // chunk*8 elems

#define GLL(SRC, DST) __builtin_amdgcn_global_load_lds((gbl_void*)(SRC), (lds_void*)(DST), 16, 0, 0)

#pragma unroll 1
    for (int t0 = 0; t0 < SEQ; t0 += 128) {
        __syncthreads();                 // prev-iter LDS readers done
#pragma unroll
        for (int o = 0; o < 4; o++) {
            const bf16* src = kh + (size_t)(t0 + krow + o * 8) * DEPTH
                            + ((kchS ^ (o & 1)) << 3);
            GLL(src, Ks + (wave * 32 + o * 8) * 64 + lane * 8);
        }
#pragma unroll
        for (int o = 0; o < 4; o++) {
            int rv = vrow + o * 4;
            const bf16* src = vh + (size_t)rv * SEQ + t0
                            + (((lane & 15) ^ (rv & 15)) << 3);
            GLL(src, Vs + (wave * 16 + o * 4) * 128 + lane * 8);
        }
        __syncthreads();                 // drains vmcnt; tile visible
        // S^T = K.Q^T  (C: row=kv=quad*4+r of half h, col=q=l16)
        f32x4 s[2][4] = {};
#pragma unroll
        for (int c = 0; c < 2; c++)
#pragma unroll
            for (int h = 0; h < 2; h++) {
                bf16x8 kf = *(const bf16x8*)&Ks[(krdRow + h * 4) * 64 +
                                                ((((c << 2) | quad) ^ ksw) << 3)];
#pragma unroll
                for (int n = 0; n < 4; n++)
                    s[h][n] = __builtin_amdgcn_mfma_f32_16x16x32_bf16(kf, bq_[n][c], s[h][n], 0, 0, 0);
            }
        // p = exp2(s): pack into PV B-fragment (k-elem = h*4 + r), lsum in VALU
        bf16x8 pb[4];
#pragma unroll
        for (int n = 0; n < 4; n++) {
#pragma unroll
            for (int h = 0; h < 2; h++) {
                float e0 = __builtin_amdgcn_exp2f(s[h][n][0]);
                float e1 = __builtin_amdgcn_exp2f(s[h][n][1]);
                float e2 = __builtin_amdgcn_exp2f(s[h][n][2]);
                float e3 = __builtin_amdgcn_exp2f(s[h][n][3]);
                pb[n][h * 4 + 0] = (bf16)e0;
                pb[n][h * 4 + 1] = (bf16)e1;
                pb[n][h * 4 + 2] = (bf16)e2;
                pb[n][h * 4 + 3] = (bf16)e3;
                lv[n] += (e0 + e1) + (e2 + e3);
            }
        }
        // ctx^T += V^T.P^T over the wave's 32-kv slice
#pragma unroll
        for (int t = 0; t < 4; t++) {
            bf16x8 vf = *(const bf16x8*)&Vs[(t * 16 + l16) * 128 + vrd];
#pragma unroll
            for (int n = 0; n < 4; n++)
                ov[t][n] = __builtin_amdgcn_mfma_f32_16x16x32_bf16(vf, pb[n], ov[t][n], 0, 0, 0);
        }
    }
#undef GLL

    // ---- cross-wave reduction of kv-partials (reuses staging LDS) ----
    f32x4* Red  = (f32x4*)smem;              // [8 tiles][4 waves][64]  32 KB
    f32x4* Lred = (f32x4*)(smem + 32768);    // [4 waves][64]            4 KB
    __syncthreads();                          // main-loop readers done
#pragma unroll
    for (int tt = 0; tt < 8; tt++)
        Red[(tt * 4 + wave) * 64 + lane] = ov[tt >> 2][tt & 3];
    Lred[wave * 64 + lane] = lv;
    __syncthreads();
    f32x4 ls = {};
#pragma unroll
    for (int w_ = 0; w_ < 4; w_++)
#pragma unroll
        for (int qd = 0; qd < 4; qd++)
            ls += Lred[w_ * 64 + qd * 16 + l16];
    const int b = bh >> 4, hh = bh & 15;
    const int wb1 = wave & 1;                 // n = wb1*2 + u (compile-time in u)
#pragma unroll
    for (int u = 0; u < 2; u++) {
        int tt = wave * 2 + u;
        f32x4 sv = Red[(tt * 4 + 0) * 64 + lane] + Red[(tt * 4 + 1) * 64 + lane]
                 + Red[(tt * 4 + 2) * 64 + lane] + Red[(tt * 4 + 3) * 64 + lane];
        int n = wb1 * 2 + u, t = wave >> 1;
        float iv = 1.0f / (wb1 ? ls[2 + u] : ls[u]);
        bf16x4 ob = {(bf16)(sv[0] * iv), (bf16)(sv[1] * iv),
                     (bf16)(sv[2] * iv), (bf16)(sv[3] * iv)};
        size_t off = ((size_t)(b * SEQ + q0 + n * 16 + l16)) * D_MODEL
                   + hh * 64 + t * 16 + quad * 4;
        *(bf16x4*)&ctx[off] = ob;
    }
    __syncthreads();
#pragma unroll
    for (int tt = 8; tt < 16; tt++)
        Red[((tt - 8) * 4 + wave) * 64 + lane] = ov[tt >> 2][tt & 3];
    __syncthreads();
#pragma unroll
    for (int u = 0; u < 2; u++) {
        int tt = 8 + wave * 2 + u;
        int rt = tt - 8;
        f32x4 sv = Red[(rt * 4 + 0) * 64 + lane] + Red[(rt * 4 + 1) * 64 + lane]
                 + Red[(rt * 4 + 2) * 64 + lane] + Red[(rt * 4 + 3) * 64 + lane];
        int n = wb1 * 2 + u, t = 2 + (wave >> 1);
        float iv = 1.0f / (wb1 ? ls[2 + u] : ls[u]);
        bf16x4 ob = {(bf16)(sv[0] * iv), (bf16)(sv[1] * iv),
                     (bf16)(sv[2] * iv), (bf16)(sv[3] * iv)};
        size_t off = ((size_t)(b * SEQ + q0 + n * 16 + l16)) * D_MODEL
                   + hh * 64 + t * 16 + quad * 4;
        *(bf16x4*)&ctx[off] = ob;
    }
}

// ---------------------------------------------------------------------------
// Kernel 4: output projection (unchanged this round).
// ---------------------------------------------------------------------------
__global__ __launch_bounds__(256) void out_gemm(const bf16* __restrict__ ctx,
                                                const bf16* __restrict__ wot,
                                                const float* __restrict__ bo,
                                                float* __restrict__ out) {
    __shared__ bf16 As[64 * 32];
    __shared__ bf16 Bs[128 * 32];
    const int tid = threadIdx.x;
    const int lane = tid & 63, wave = tid >> 6;
    const int quad = lane >> 4, l16 = lane & 15;
    const int srow = lane >> 2, selem = (lane & 3) * 8;
    int row0 = blockIdx.y * 64, col0 = blockIdx.x * 128;
    f32x4 acc[4][2] = {};

    for (int k0 = 0; k0 < D_MODEL; k0 += 32) {
        __syncthreads();
        {
            const bf16* ga = ctx + (size_t)(row0 + wave * 16 + srow) * D_MODEL + k0 + selem;
            __builtin_amdgcn_global_load_lds((gbl_void*)ga, (lds_void*)(As + wave * 512 + lane * 8), 16, 0, 0);
        }
#pragma unroll
        for (int t = 0; t < 2; t++) {
            int m = wave * 2 + t;
            const bf16* gb = wot + (size_t)(col0 + m * 16 + srow) * D_MODEL + k0 + selem;
            __builtin_amdgcn_global_load_lds((gbl_void*)gb, (lds_void*)(Bs + m * 512 + lane * 8), 16, 0, 0);
        }
        __syncthreads();
        bf16x8 af[4], bfr[2];
#pragma unroll
        for (int i = 0; i < 4; i++)
            af[i] = *(const bf16x8*)&As[(i * 16 + l16) * 32 + quad * 8];
#pragma unroll
        for (int j = 0; j < 2; j++)
            bfr[j] = *(const bf16x8*)&Bs[(wave * 32 + j * 16 + l16) * 32 + quad * 8];
#pragma unroll
        for (int i = 0; i < 4; i++)
#pragma unroll
            for (int j = 0; j < 2; j++)
                acc[i][j] = __builtin_amdgcn_mfma_f32_16x16x32_bf16(af[i], bfr[j], acc[i][j], 0, 0, 0);
    }
#pragma unroll
    for (int i = 0; i < 4; i++)
#pragma unroll
        for (int j = 0; j < 2; j++) {
            int colg = col0 + wave * 32 + j * 16 + l16;
            float bi = bo[colg];
            int rbase = row0 + i * 16 + quad * 4;
#pragma unroll
            for (int r = 0; r < 4; r++)
                out[(size_t)(rbase + r) * D_MODEL + colg] = acc[i][j][r] + bi;
        }
}

// ---------------------------------------------------------------------------
extern "C" void kernel_launch(void* const* d_in, const int* in_sizes, int n_in,
                              void* d_out, int out_size, void* d_ws, size_t ws_size,
                              hipStream_t stream) {
    const float* x  = (const float*)d_in[0];
    const float* wq = (const float*)d_in[1];
    const float* bq = (const float*)d_in[2];
    const float* wk = (const float*)d_in[3];
    const float* bk = (const float*)d_in[4];
    const float* wv = (const float*)d_in[5];
    const float* bv = (const float*)d_in[6];
    const float* wo = (const float*)d_in[7];
    const float* bo = (const float*)d_in[8];
    float* out = (float*)d_out;

    const size_t MB = 1024 * 1024;
    char* ws = (char*)d_ws;
    bf16* xb  = (bf16*)(ws);             // [4096][1024]            8 MB
    bf16* wtb = (bf16*)(ws + 8 * MB);    // [4][1024][1024] (N,K)   8 MB
    bf16* qb  = (bf16*)(ws + 16 * MB);   // [B,H,S,64] (scaled)     8 MB
    bf16* kb  = (bf16*)(ws + 24 * MB);   // [B,H,S,64]              8 MB
    bf16* vb  = (bf16*)(ws + 32 * MB);   // [B,H,64,S]              8 MB
    bf16* ctx = (bf16*)(ws + 40 * MB);   // [4096][1024]            8 MB

    prep<<<dim3(32, 32, 8), dim3(32, 8), 0, stream>>>(wq, wk, wv, wo, x, wtb, xb);
    qkv_gemm<<<dim3(192), dim3(512), 0, stream>>>(xb, wtb, bq, bk, bv, qb, kb, vb);
    attn<<<dim3(BATCH * NHEAD, SEQ / 64), 256, 0, stream>>>(qb, kb, vb, ctx);
    out_gemm<<<dim3(8, 64), 256, 0, stream>>>(ctx, wtb + 3 * (size_t)D_MODEL * D_MODEL, bo, out);
}